// Round 1
// baseline (632.797 us; speedup 1.0000x reference)
//
#include <hip/hip_runtime.h>
#include <hip/hip_bf16.h>

// ---------------------------------------------------------------------------
// simple_GCN: 3-layer GCNConv (N=10000, E=160000, 128->1000->700->200) +
// global mean pool over 64 graphs + linear to 10 classes. fp32 baseline.
//
// Key algebraic move: GCN aggregation A~ = D^-1/2 (A + ... ) commutes with
// the dense weight: A~(xW) = (A~x)W.  Layer 1 aggregates BEFORE the GEMM
// (128 dims instead of 1000); layers 2/3 aggregate AFTER (700/200 dims).
// CSR-by-dst is built on device every call (no atomic feature scatter).
// ---------------------------------------------------------------------------

#define SCAN_BS 256

__global__ void k_zero_int(int* __restrict__ p, int n) {
    int i = blockIdx.x * blockDim.x + threadIdx.x;
    if (i < n) p[i] = 0;
}

__global__ void k_count_deg(const int* __restrict__ dst, int* __restrict__ degi, int E) {
    int e = blockIdx.x * blockDim.x + threadIdx.x;
    if (e < E) atomicAdd(&degi[dst[e]], 1);
}

__global__ void k_dinv(const int* __restrict__ degi, float* __restrict__ dinv, int N) {
    int i = blockIdx.x * blockDim.x + threadIdx.x;
    if (i < N) dinv[i] = rsqrtf((float)degi[i] + 1.0f);
}

// inclusive scan within 256-block; block totals to partial[]
__global__ void k_scan1(const int* __restrict__ degi, int* __restrict__ incl,
                        int* __restrict__ partial, int N) {
    __shared__ int s[SCAN_BS];
    int t = threadIdx.x;
    int i = blockIdx.x * SCAN_BS + t;
    int v = (i < N) ? degi[i] : 0;
    s[t] = v;
    __syncthreads();
    for (int o = 1; o < SCAN_BS; o <<= 1) {
        int add = (t >= o) ? s[t - o] : 0;
        __syncthreads();
        if (t >= o) s[t] += add;
        __syncthreads();
    }
    if (i < N) incl[i] = s[t];
    if (t == SCAN_BS - 1) partial[blockIdx.x] = s[t];
}

// single block: exclusive scan of up to 256 block partials
__global__ void k_scan2(const int* __restrict__ partial, int* __restrict__ part_excl, int nb) {
    __shared__ int s[SCAN_BS];
    int t = threadIdx.x;
    int v = (t < nb) ? partial[t] : 0;
    s[t] = v;
    __syncthreads();
    for (int o = 1; o < SCAN_BS; o <<= 1) {
        int add = (t >= o) ? s[t - o] : 0;
        __syncthreads();
        if (t >= o) s[t] += add;
        __syncthreads();
    }
    if (t < nb) part_excl[t] = s[t] - v;
}

__global__ void k_scan3(const int* __restrict__ incl, const int* __restrict__ degi,
                        const int* __restrict__ part_excl, int* __restrict__ row_ptr,
                        int* __restrict__ cursor, int N) {
    int i = blockIdx.x * blockDim.x + threadIdx.x;
    if (i < N) {
        int rp = incl[i] - degi[i] + part_excl[i >> 8];
        row_ptr[i] = rp;
        cursor[i]  = rp;
        if (i == N - 1) row_ptr[N] = rp + degi[i];
    }
}

__global__ void k_scatter(const int* __restrict__ src, const int* __restrict__ dst,
                          const float* __restrict__ dinv, int* __restrict__ cursor,
                          int* __restrict__ src_s, float* __restrict__ coef_s, int E) {
    int e = blockIdx.x * blockDim.x + threadIdx.x;
    if (e < E) {
        int s = src[e], d = dst[e];
        int pos = atomicAdd(&cursor[d], 1);
        src_s[pos]  = s;
        coef_s[pos] = dinv[s] * dinv[d];
    }
}

// out[i,:] = act( sum_{e: dst=i} coef_e * in[src_e,:] + dinv[i]^2 * in[i,:] + bias )
// one block per node; threads cover feature dim as float4
__global__ void k_aggregate(const float* __restrict__ in, float* __restrict__ out,
                            const int* __restrict__ row_ptr, const int* __restrict__ src_s,
                            const float* __restrict__ coef_s, const float* __restrict__ dinv,
                            const float* __restrict__ bias, int H, int do_relu) {
    int node = blockIdx.x;
    int H4 = H >> 2;
    const float4* in4 = (const float4*)in;
    float4* out4 = (float4*)out;
    int rs = row_ptr[node], re = row_ptr[node + 1];
    float self = dinv[node];
    self *= self;
    for (int j = threadIdx.x; j < H4; j += blockDim.x) {
        float4 xv = in4[(size_t)node * H4 + j];
        float ax = self * xv.x, ay = self * xv.y, az = self * xv.z, aw = self * xv.w;
        for (int e = rs; e < re; ++e) {
            float c = coef_s[e];
            int s = src_s[e];
            float4 hv = in4[(size_t)s * H4 + j];
            ax += c * hv.x; ay += c * hv.y; az += c * hv.z; aw += c * hv.w;
        }
        if (bias) {
            float4 bv = ((const float4*)bias)[j];
            ax += bv.x; ay += bv.y; az += bv.z; aw += bv.w;
        }
        if (do_relu) {
            ax = fmaxf(ax, 0.f); ay = fmaxf(ay, 0.f);
            az = fmaxf(az, 0.f); aw = fmaxf(aw, 0.f);
        }
        float4 o; o.x = ax; o.y = ay; o.z = az; o.w = aw;
        out4[(size_t)node * H4 + j] = o;
    }
}

// fp32 tiled GEMM: C[M,N] = act(A[M,K] @ B[K,N] + bias)
// 64x64 tile, BK=16, 256 threads, 4x4 per thread
#define TBM 64
#define TBN 64
#define TBK 16
__global__ __launch_bounds__(256) void k_gemm(
    const float* __restrict__ A, const float* __restrict__ B,
    const float* __restrict__ bias, float* __restrict__ C,
    int M, int N, int K, int do_relu) {
    __shared__ float As[TBK][TBM + 4];
    __shared__ float Bs[TBK][TBN + 4];
    int tid = threadIdx.x;
    int row0 = blockIdx.y * TBM, col0 = blockIdx.x * TBN;
    int arow = tid >> 2;          // 0..63
    int ak   = (tid & 3) << 2;    // 0,4,8,12
    int brow = tid >> 4;          // 0..15
    int bcol = (tid & 15) << 2;   // 0..60
    int tm = (tid >> 4) << 2;     // output row base
    int tn = (tid & 15) << 2;     // output col base
    float acc[4][4] = {};
    for (int k0 = 0; k0 < K; k0 += TBK) {
        float4 av = make_float4(0.f, 0.f, 0.f, 0.f);
        if (row0 + arow < M && k0 + ak < K)
            av = *(const float4*)&A[(size_t)(row0 + arow) * K + k0 + ak];
        float4 bv = make_float4(0.f, 0.f, 0.f, 0.f);
        if (k0 + brow < K && col0 + bcol < N)
            bv = *(const float4*)&B[(size_t)(k0 + brow) * N + col0 + bcol];
        As[ak + 0][arow] = av.x;
        As[ak + 1][arow] = av.y;
        As[ak + 2][arow] = av.z;
        As[ak + 3][arow] = av.w;
        *(float4*)&Bs[brow][bcol] = bv;
        __syncthreads();
#pragma unroll
        for (int kk = 0; kk < TBK; ++kk) {
            float4 a = *(const float4*)&As[kk][tm];
            float4 b = *(const float4*)&Bs[kk][tn];
            acc[0][0] += a.x * b.x; acc[0][1] += a.x * b.y; acc[0][2] += a.x * b.z; acc[0][3] += a.x * b.w;
            acc[1][0] += a.y * b.x; acc[1][1] += a.y * b.y; acc[1][2] += a.y * b.z; acc[1][3] += a.y * b.w;
            acc[2][0] += a.z * b.x; acc[2][1] += a.z * b.y; acc[2][2] += a.z * b.z; acc[2][3] += a.z * b.w;
            acc[3][0] += a.w * b.x; acc[3][1] += a.w * b.y; acc[3][2] += a.w * b.z; acc[3][3] += a.w * b.w;
        }
        __syncthreads();
    }
    if (col0 + tn < N) {
        float4 bv = make_float4(0.f, 0.f, 0.f, 0.f);
        if (bias) bv = *(const float4*)&bias[col0 + tn];
#pragma unroll
        for (int i = 0; i < 4; ++i) {
            int row = row0 + tm + i;
            if (row < M) {
                float4 v;
                v.x = acc[i][0] + bv.x; v.y = acc[i][1] + bv.y;
                v.z = acc[i][2] + bv.z; v.w = acc[i][3] + bv.w;
                if (do_relu) {
                    v.x = fmaxf(v.x, 0.f); v.y = fmaxf(v.y, 0.f);
                    v.z = fmaxf(v.z, 0.f); v.w = fmaxf(v.w, 0.f);
                }
                *(float4*)&C[(size_t)row * N + col0 + tn] = v;
            }
        }
    }
}

// mean pool per graph (batch sorted) — one block per graph
__global__ void k_pool(const float* __restrict__ h, const int* __restrict__ batch,
                       float* __restrict__ pooled, int N, int H) {
    int g = blockIdx.x;
    int lo = 0, hi = N;
    while (lo < hi) { int mid = (lo + hi) >> 1; if (batch[mid] < g) lo = mid + 1; else hi = mid; }
    int start = lo;
    lo = start; hi = N;
    while (lo < hi) { int mid = (lo + hi) >> 1; if (batch[mid] < g + 1) lo = mid + 1; else hi = mid; }
    int end = lo;
    float denom = fmaxf((float)(end - start), 1.0f);
    for (int j = threadIdx.x; j < H; j += blockDim.x) {
        float acc = 0.f;
        for (int i = start; i < end; ++i) acc += h[(size_t)i * H + j];
        pooled[(size_t)g * H + j] = acc / denom;
    }
}

__global__ void k_classifier(const float* __restrict__ pooled, const float* __restrict__ Wl,
                             const float* __restrict__ bl, float* __restrict__ out,
                             int H, int NC) {
    int g = blockIdx.x;
    int c = threadIdx.x;
    if (c < NC) {
        float acc = bl[c];
        for (int k = 0; k < H; ++k) acc += pooled[(size_t)g * H + k] * Wl[(size_t)k * NC + c];
        out[(size_t)g * NC + c] = acc;
    }
}

static inline size_t align256(size_t x) { return (x + 255) & ~(size_t)255; }

extern "C" void kernel_launch(void* const* d_in, const int* in_sizes, int n_in,
                              void* d_out, int out_size, void* d_ws, size_t ws_size,
                              hipStream_t stream) {
    const float* x   = (const float*)d_in[0];
    const int*   ei  = (const int*)d_in[1];
    const int*   bat = (const int*)d_in[2];
    const float* W1  = (const float*)d_in[3];
    const float* b1  = (const float*)d_in[4];
    const float* W2  = (const float*)d_in[5];
    const float* b2  = (const float*)d_in[6];
    const float* W3  = (const float*)d_in[7];
    const float* b3  = (const float*)d_in[8];
    const float* Wl  = (const float*)d_in[9];
    const float* bl  = (const float*)d_in[10];

    const int N  = in_sizes[2];
    const int E  = in_sizes[1] / 2;
    const int F  = in_sizes[0] / N;    // 128
    const int H1 = in_sizes[4];        // 1000
    const int H2 = in_sizes[6];        // 700
    const int H3 = in_sizes[8];        // 200
    const int NC = in_sizes[10];       // 10
    const int G  = out_size / NC;      // 64
    const int* src = ei;
    const int* dst = ei + E;

    int maxH = F;
    if (H1 > maxH) maxH = H1;
    if (H2 > maxH) maxH = H2;
    if (H3 > maxH) maxH = H3;

    // workspace carve
    char* p = (char*)d_ws;
    size_t off = 0;
    auto carve = [&](size_t bytes) { void* q = p + off; off += align256(bytes); return q; };
    float* bufA     = (float*)carve((size_t)N * maxH * 4);
    float* bufB     = (float*)carve((size_t)N * maxH * 4);
    float* dinv     = (float*)carve((size_t)N * 4);
    int*   degi     = (int*)carve((size_t)N * 4);
    int*   incl     = (int*)carve((size_t)N * 4);
    int*   partial  = (int*)carve(256 * 4);
    int*   pexcl    = (int*)carve(256 * 4);
    int*   row_ptr  = (int*)carve((size_t)(N + 1) * 4);
    int*   cursor   = (int*)carve((size_t)N * 4);
    int*   src_s    = (int*)carve((size_t)E * 4);
    float* coef_s   = (float*)carve((size_t)E * 4);
    float* pooled   = (float*)carve((size_t)G * H3 * 4);
    (void)ws_size;

    const int nbN = (N + 255) / 256;
    const int nbE = (E + 255) / 256;

    // ---- degree + dinv + CSR build ----
    k_zero_int<<<nbN, 256, 0, stream>>>(degi, N);
    k_count_deg<<<nbE, 256, 0, stream>>>(dst, degi, E);
    k_dinv<<<nbN, 256, 0, stream>>>(degi, dinv, N);
    k_scan1<<<nbN, SCAN_BS, 0, stream>>>(degi, incl, partial, N);
    k_scan2<<<1, SCAN_BS, 0, stream>>>(partial, pexcl, nbN);
    k_scan3<<<nbN, 256, 0, stream>>>(incl, degi, pexcl, row_ptr, cursor, N);
    k_scatter<<<nbE, 256, 0, stream>>>(src, dst, dinv, cursor, src_s, coef_s, E);

    auto agg_block = [](int H) {
        int b = ((H / 4 + 63) / 64) * 64;
        if (b > 256) b = 256;
        if (b < 64) b = 64;
        return b;
    };
    auto gemm_grid = [](int M, int Nn) { return dim3((Nn + TBN - 1) / TBN, (M + TBM - 1) / TBM); };

    // ---- layer 1: aggregate(x) [N,128] then GEMM+b1+relu -> bufB [N,1000]
    k_aggregate<<<N, agg_block(F), 0, stream>>>(x, bufA, row_ptr, src_s, coef_s, dinv,
                                                nullptr, F, 0);
    k_gemm<<<gemm_grid(N, H1), 256, 0, stream>>>(bufA, W1, b1, bufB, N, H1, F, 1);

    // ---- layer 2: GEMM -> bufA [N,700]; aggregate+b2+relu -> bufB [N,700]
    k_gemm<<<gemm_grid(N, H2), 256, 0, stream>>>(bufB, W2, nullptr, bufA, N, H2, H1, 0);
    k_aggregate<<<N, agg_block(H2), 0, stream>>>(bufA, bufB, row_ptr, src_s, coef_s, dinv,
                                                 b2, H2, 1);

    // ---- layer 3: GEMM -> bufA [N,200]; aggregate+b3+relu -> bufB [N,200]
    k_gemm<<<gemm_grid(N, H3), 256, 0, stream>>>(bufB, W3, nullptr, bufA, N, H3, H2, 0);
    k_aggregate<<<N, agg_block(H3), 0, stream>>>(bufA, bufB, row_ptr, src_s, coef_s, dinv,
                                                 b3, H3, 1);

    // ---- pool + classifier ----
    k_pool<<<G, 256, 0, stream>>>(bufB, bat, pooled, N, H3);
    k_classifier<<<G, 64, 0, stream>>>(pooled, Wl, bl, (float*)d_out, H3, NC);
}

// Round 2
// 347.668 us; speedup vs baseline: 1.8201x; 1.8201x over previous
//
#include <hip/hip_runtime.h>
#include <hip/hip_bf16.h>
#include <stdint.h>

// ---------------------------------------------------------------------------
// simple_GCN: 3-layer GCNConv (N=10000, E=160000, 128->1000->700->200) +
// global mean pool (64 graphs) + linear(10).
//
// R2: bf16 MFMA GEMMs (m97 structure: 128x128 tile, BK=32, 16x16x32_bf16,
// global_load_lds width=16). Weights transpose-converted fp32->bf16 zero-
// padded each call, so padded K-cols contribute exactly 0 and all tiles are
// full. Activations bf16 between layers (halves gather bytes); aggregation
// accumulates fp32; layer-3 GEMM output + final agg/pool/classifier fp32.
// ---------------------------------------------------------------------------

#define SCAN_BS 256

__device__ __forceinline__ uint16_t f2b(float f) {           // fp32->bf16 RNE
    union { float f; uint32_t u; } v; v.f = f;
    return (uint16_t)((v.u + 0x7fffu + ((v.u >> 16) & 1u)) >> 16);
}
__device__ __forceinline__ float blo(uint32_t u) { union { uint32_t u; float f; } v; v.u = u << 16; return v.f; }
__device__ __forceinline__ float bhi(uint32_t u) { union { uint32_t u; float f; } v; v.u = u & 0xffff0000u; return v.f; }

// ---------------- CSR build ----------------
__global__ void k_zero_int(int* __restrict__ p, int n) {
    int i = blockIdx.x * blockDim.x + threadIdx.x;
    if (i < n) p[i] = 0;
}
__global__ void k_count_deg(const int* __restrict__ dst, int* __restrict__ degi, int E) {
    int e = blockIdx.x * blockDim.x + threadIdx.x;
    if (e < E) atomicAdd(&degi[dst[e]], 1);
}
__global__ void k_dinv(const int* __restrict__ degi, float* __restrict__ dinv, int N) {
    int i = blockIdx.x * blockDim.x + threadIdx.x;
    if (i < N) dinv[i] = rsqrtf((float)degi[i] + 1.0f);
}
__global__ void k_scan1(const int* __restrict__ degi, int* __restrict__ incl,
                        int* __restrict__ partial, int N) {
    __shared__ int s[SCAN_BS];
    int t = threadIdx.x, i = blockIdx.x * SCAN_BS + t;
    int v = (i < N) ? degi[i] : 0;
    s[t] = v; __syncthreads();
    for (int o = 1; o < SCAN_BS; o <<= 1) {
        int add = (t >= o) ? s[t - o] : 0; __syncthreads();
        if (t >= o) s[t] += add; __syncthreads();
    }
    if (i < N) incl[i] = s[t];
    if (t == SCAN_BS - 1) partial[blockIdx.x] = s[t];
}
__global__ void k_scan2(const int* __restrict__ partial, int* __restrict__ part_excl, int nb) {
    __shared__ int s[SCAN_BS];
    int t = threadIdx.x;
    int v = (t < nb) ? partial[t] : 0;
    s[t] = v; __syncthreads();
    for (int o = 1; o < SCAN_BS; o <<= 1) {
        int add = (t >= o) ? s[t - o] : 0; __syncthreads();
        if (t >= o) s[t] += add; __syncthreads();
    }
    if (t < nb) part_excl[t] = s[t] - v;
}
__global__ void k_scan3(const int* __restrict__ incl, const int* __restrict__ degi,
                        const int* __restrict__ part_excl, int* __restrict__ row_ptr,
                        int* __restrict__ cursor, int N) {
    int i = blockIdx.x * blockDim.x + threadIdx.x;
    if (i < N) {
        int rp = incl[i] - degi[i] + part_excl[i >> 8];
        row_ptr[i] = rp; cursor[i] = rp;
        if (i == N - 1) row_ptr[N] = rp + degi[i];
    }
}
__global__ void k_scatter(const int* __restrict__ src, const int* __restrict__ dst,
                          const float* __restrict__ dinv, int* __restrict__ cursor,
                          int* __restrict__ src_s, float* __restrict__ coef_s, int E) {
    int e = blockIdx.x * blockDim.x + threadIdx.x;
    if (e < E) {
        int s = src[e], d = dst[e];
        int pos = atomicAdd(&cursor[d], 1);
        src_s[pos]  = s;
        coef_s[pos] = dinv[s] * dinv[d];
    }
}

// ---------------- weight transpose-convert (fp32 [K x N] -> bf16 [Np x Kp], zero-padded)
__global__ void k_wt(const float* __restrict__ W, uint16_t* __restrict__ Wt,
                     int K, int Nn, int Kp, int Np) {
    __shared__ float tile[32][33];
    int k0 = blockIdx.x * 32, n0 = blockIdx.y * 32;
    int tx = threadIdx.x, ty = threadIdx.y;  // 32 x 8
    for (int i = ty; i < 32; i += 8) {
        int k = k0 + i, n = n0 + tx;
        tile[i][tx] = (k < K && n < Nn) ? W[(size_t)k * Nn + n] : 0.f;
    }
    __syncthreads();
    for (int i = ty; i < 32; i += 8) {
        int n = n0 + i, k = k0 + tx;
        Wt[(size_t)n * Kp + k] = f2b(tile[tx][i]);
    }
}
__global__ void k_biaspad(const float* __restrict__ b, float* __restrict__ bp, int H, int Hp) {
    int i = blockIdx.x * blockDim.x + threadIdx.x;
    if (i < Hp) bp[i] = (i < H) ? b[i] : 0.f;
}

// ---------------- aggregation ----------------
// fp32 in, chunk=4; out fp32 or bf16
__global__ void k_agg_f32(const float* __restrict__ in, void* __restrict__ out,
                          const int* __restrict__ row_ptr, const int* __restrict__ src_s,
                          const float* __restrict__ coef_s, const float* __restrict__ dinv,
                          const float* __restrict__ bias, int Hp, int relu, int out_bf16) {
    int node = blockIdx.y;
    int j = blockIdx.x * blockDim.x + threadIdx.x;
    int Hc = Hp >> 2;
    if (j >= Hc) return;
    int rs = row_ptr[node], re = row_ptr[node + 1];
    float self = dinv[node]; self *= self;
    const float4* in4 = (const float4*)in;
    float4 xv = in4[(size_t)node * Hc + j];
    float a0 = self * xv.x, a1 = self * xv.y, a2 = self * xv.z, a3 = self * xv.w;
    for (int e = rs; e < re; ++e) {
        float c = coef_s[e]; int s = src_s[e];
        float4 hv = in4[(size_t)s * Hc + j];
        a0 += c * hv.x; a1 += c * hv.y; a2 += c * hv.z; a3 += c * hv.w;
    }
    if (bias) { float4 bv = ((const float4*)bias)[j]; a0 += bv.x; a1 += bv.y; a2 += bv.z; a3 += bv.w; }
    if (relu) { a0 = fmaxf(a0, 0.f); a1 = fmaxf(a1, 0.f); a2 = fmaxf(a2, 0.f); a3 = fmaxf(a3, 0.f); }
    if (out_bf16) {
        uint2 o;
        o.x = (uint32_t)f2b(a0) | ((uint32_t)f2b(a1) << 16);
        o.y = (uint32_t)f2b(a2) | ((uint32_t)f2b(a3) << 16);
        ((uint2*)out)[(size_t)node * Hc + j] = o;
    } else {
        float4 o; o.x = a0; o.y = a1; o.z = a2; o.w = a3;
        ((float4*)out)[(size_t)node * Hc + j] = o;
    }
}
// bf16 in/out, chunk=8 (uint4 = 16B)
__global__ void k_agg_b16(const uint16_t* __restrict__ in, uint16_t* __restrict__ out,
                          const int* __restrict__ row_ptr, const int* __restrict__ src_s,
                          const float* __restrict__ coef_s, const float* __restrict__ dinv,
                          const float* __restrict__ bias, int Hp, int relu) {
    int node = blockIdx.y;
    int j = blockIdx.x * blockDim.x + threadIdx.x;
    int Hc = Hp >> 3;
    if (j >= Hc) return;
    int rs = row_ptr[node], re = row_ptr[node + 1];
    float self = dinv[node]; self *= self;
    const uint4* in4 = (const uint4*)in;
    uint4 v = in4[(size_t)node * Hc + j];
    float a[8];
    a[0] = self * blo(v.x); a[1] = self * bhi(v.x);
    a[2] = self * blo(v.y); a[3] = self * bhi(v.y);
    a[4] = self * blo(v.z); a[5] = self * bhi(v.z);
    a[6] = self * blo(v.w); a[7] = self * bhi(v.w);
    for (int e = rs; e < re; ++e) {
        float c = coef_s[e]; int s = src_s[e];
        uint4 h = in4[(size_t)s * Hc + j];
        a[0] += c * blo(h.x); a[1] += c * bhi(h.x);
        a[2] += c * blo(h.y); a[3] += c * bhi(h.y);
        a[4] += c * blo(h.z); a[5] += c * bhi(h.z);
        a[6] += c * blo(h.w); a[7] += c * bhi(h.w);
    }
    if (bias) {
        const float4* b4 = (const float4*)bias;
        float4 b0 = b4[2 * j], b1 = b4[2 * j + 1];
        a[0] += b0.x; a[1] += b0.y; a[2] += b0.z; a[3] += b0.w;
        a[4] += b1.x; a[5] += b1.y; a[6] += b1.z; a[7] += b1.w;
    }
    if (relu) {
#pragma unroll
        for (int t = 0; t < 8; ++t) a[t] = fmaxf(a[t], 0.f);
    }
    uint4 o;
    o.x = (uint32_t)f2b(a[0]) | ((uint32_t)f2b(a[1]) << 16);
    o.y = (uint32_t)f2b(a[2]) | ((uint32_t)f2b(a[3]) << 16);
    o.z = (uint32_t)f2b(a[4]) | ((uint32_t)f2b(a[5]) << 16);
    o.w = (uint32_t)f2b(a[6]) | ((uint32_t)f2b(a[7]) << 16);
    ((uint4*)out)[(size_t)node * Hc + j] = o;
}

// ---------------- bf16 MFMA GEMM: C[M,Np] = act(A[Mp,Kp] @ Bt[Np,Kp]^T + bias)
typedef __attribute__((ext_vector_type(8))) short short8;
typedef __attribute__((ext_vector_type(4))) float floatx4;

#define LDSP(p) ((__attribute__((address_space(3))) void*)(uintptr_t)(p))
#define GLBP(p) ((const __attribute__((address_space(1))) void*)(uintptr_t)(p))

__global__ __launch_bounds__(256) void k_gemm_bf16(
    const uint16_t* __restrict__ A,   // [Mp x Kp] row-major, Kp%32==0
    const uint16_t* __restrict__ Bt,  // [Np x Kp] row-major (= W transposed)
    const float* __restrict__ bias,   // [Np] padded, or null
    void* __restrict__ Cout,          // bf16 or fp32 [.. x Np]
    int M, int Kp, int Np, int relu, int out_bf16) {
    __shared__ uint16_t As[128 * 32];
    __shared__ uint16_t Bs[128 * 32];
    int tid = threadIdx.x;
    int wave = tid >> 6, lane = tid & 63;
    int quad = lane >> 4, m16 = lane & 15;
    int wr = wave >> 1, wc = wave & 1;
    int row0 = blockIdx.y * 128, col0 = blockIdx.x * 128;

    int rA = tid >> 2, cA = tid & 3;            // staging: row, 16B chunk
    const uint16_t* gA = A  + (size_t)(row0 + rA) * Kp + cA * 8;
    const uint16_t* gB = Bt + (size_t)(col0 + rA) * Kp + cA * 8;
    uint16_t* lA = As + tid * 8;                // dst = wave base + lane*16B
    uint16_t* lB = Bs + tid * 8;
    size_t rowStep = (size_t)64 * Kp;

    floatx4 acc[4][4];
#pragma unroll
    for (int i = 0; i < 4; ++i)
#pragma unroll
        for (int j = 0; j < 4; ++j) acc[i][j] = (floatx4){0.f, 0.f, 0.f, 0.f};

    const short* Ash = (const short*)As;
    const short* Bsh = (const short*)Bs;
    int aBase = (wr * 64 + m16) * 32 + quad * 8;
    int bBase = (wc * 64 + m16) * 32 + quad * 8;

    for (int k0 = 0; k0 < Kp; k0 += 32) {
        __builtin_amdgcn_global_load_lds(GLBP(gA),           LDSP(lA),        16, 0, 0);
        __builtin_amdgcn_global_load_lds(GLBP(gA + rowStep), LDSP(lA + 2048), 16, 0, 0);
        __builtin_amdgcn_global_load_lds(GLBP(gB),           LDSP(lB),        16, 0, 0);
        __builtin_amdgcn_global_load_lds(GLBP(gB + rowStep), LDSP(lB + 2048), 16, 0, 0);
        gA += 32; gB += 32;
        __syncthreads();
        short8 af[4], bf[4];
#pragma unroll
        for (int i = 0; i < 4; ++i) af[i] = *(const short8*)&Ash[aBase + i * 512];
#pragma unroll
        for (int j = 0; j < 4; ++j) bf[j] = *(const short8*)&Bsh[bBase + j * 512];
#pragma unroll
        for (int i = 0; i < 4; ++i)
#pragma unroll
            for (int j = 0; j < 4; ++j)
                acc[i][j] = __builtin_amdgcn_mfma_f32_16x16x32_bf16(af[i], bf[j], acc[i][j], 0, 0, 0);
        __syncthreads();
    }

    float bv[4];
#pragma unroll
    for (int j = 0; j < 4; ++j) {
        int n = col0 + wc * 64 + j * 16 + m16;
        bv[j] = bias ? bias[n] : 0.f;
    }
#pragma unroll
    for (int i = 0; i < 4; ++i) {
        int mBase = row0 + wr * 64 + i * 16 + quad * 4;
#pragma unroll
        for (int r = 0; r < 4; ++r) {
            int m = mBase + r;
            if (m < M) {
#pragma unroll
                for (int j = 0; j < 4; ++j) {
                    int n = col0 + wc * 64 + j * 16 + m16;
                    float v = acc[i][j][r] + bv[j];
                    if (relu) v = fmaxf(v, 0.f);
                    if (out_bf16) ((uint16_t*)Cout)[(size_t)m * Np + n] = f2b(v);
                    else          ((float*)Cout)[(size_t)m * Np + n]    = v;
                }
            }
        }
    }
}

// ---------------- pool + classifier ----------------
__global__ void k_pool(const float* __restrict__ h, const int* __restrict__ batch,
                       float* __restrict__ pooled, int N, int H, int stride) {
    int g = blockIdx.x;
    int lo = 0, hi = N;
    while (lo < hi) { int mid = (lo + hi) >> 1; if (batch[mid] < g) lo = mid + 1; else hi = mid; }
    int start = lo;
    lo = start; hi = N;
    while (lo < hi) { int mid = (lo + hi) >> 1; if (batch[mid] < g + 1) lo = mid + 1; else hi = mid; }
    int end = lo;
    float denom = fmaxf((float)(end - start), 1.0f);
    for (int j = threadIdx.x; j < H; j += blockDim.x) {
        float acc = 0.f;
        for (int i = start; i < end; ++i) acc += h[(size_t)i * stride + j];
        pooled[(size_t)g * H + j] = acc / denom;
    }
}
__global__ void k_classifier(const float* __restrict__ pooled, const float* __restrict__ Wl,
                             const float* __restrict__ bl, float* __restrict__ out,
                             int H, int NC) {
    int g = blockIdx.x, c = threadIdx.x;
    if (c < NC) {
        float acc = bl[c];
        for (int k = 0; k < H; ++k) acc += pooled[(size_t)g * H + k] * Wl[(size_t)k * NC + c];
        out[(size_t)g * NC + c] = acc;
    }
}

static inline size_t align256(size_t x) { return (x + 255) & ~(size_t)255; }
static inline int pad128(int x) { return (x + 127) & ~127; }

extern "C" void kernel_launch(void* const* d_in, const int* in_sizes, int n_in,
                              void* d_out, int out_size, void* d_ws, size_t ws_size,
                              hipStream_t stream) {
    const float* x   = (const float*)d_in[0];
    const int*   ei  = (const int*)d_in[1];
    const int*   bat = (const int*)d_in[2];
    const float* W1  = (const float*)d_in[3];
    const float* b1  = (const float*)d_in[4];
    const float* W2  = (const float*)d_in[5];
    const float* b2  = (const float*)d_in[6];
    const float* W3  = (const float*)d_in[7];
    const float* b3  = (const float*)d_in[8];
    const float* Wl  = (const float*)d_in[9];
    const float* bl  = (const float*)d_in[10];

    const int N  = in_sizes[2];
    const int E  = in_sizes[1] / 2;
    const int F  = in_sizes[0] / N;    // 128
    const int H1 = in_sizes[4];        // 1000
    const int H2 = in_sizes[6];        // 700
    const int H3 = in_sizes[8];        // 200
    const int NC = in_sizes[10];       // 10
    const int* src = ei;
    const int* dst = ei + E;

    const int Mp  = pad128(N);         // 10112
    const int Fp  = F;                 // 128 (already 128-mult)
    const int H1p = pad128(H1);        // 1024
    const int H2p = pad128(H2);        // 768
    const int H3p = pad128(H3);        // 256

    // workspace carve
    char* p = (char*)d_ws;
    size_t off = 0;
    auto carve = [&](size_t bytes) { void* q = p + off; off += align256(bytes); return q; };
    uint16_t* bufA   = (uint16_t*)carve((size_t)Mp * 2048);       // bf16 Mp x <=768 / fp32 Mp x 256
    uint16_t* bufB   = (uint16_t*)carve((size_t)Mp * 2048);       // bf16 Mp x 1024 / fp32 Mp x 256
    uint16_t* W1t    = (uint16_t*)carve((size_t)H1p * Fp * 2);
    uint16_t* W2t    = (uint16_t*)carve((size_t)H2p * H1p * 2);
    uint16_t* W3t    = (uint16_t*)carve((size_t)H3p * H2p * 2);
    float* b1p       = (float*)carve((size_t)H1p * 4);
    float* b2p       = (float*)carve((size_t)H2p * 4);
    float* b3p       = (float*)carve((size_t)H3p * 4);
    float* dinv      = (float*)carve((size_t)N * 4);
    int*   degi      = (int*)carve((size_t)N * 4);
    int*   incl      = (int*)carve((size_t)N * 4);
    int*   partial   = (int*)carve(256 * 4);
    int*   pexcl     = (int*)carve(256 * 4);
    int*   row_ptr   = (int*)carve((size_t)(N + 1) * 4);
    int*   cursor    = (int*)carve((size_t)N * 4);
    int*   src_s     = (int*)carve((size_t)E * 4);
    float* coef_s    = (float*)carve((size_t)E * 4);
    float* pooled    = (float*)carve((size_t)64 * H3 * 4);
    (void)ws_size;

    const int nbN = (N + 255) / 256;
    const int nbE = (E + 255) / 256;

    // ---- CSR build ----
    k_zero_int<<<nbN, 256, 0, stream>>>(degi, N);
    k_count_deg<<<nbE, 256, 0, stream>>>(dst, degi, E);
    k_dinv<<<nbN, 256, 0, stream>>>(degi, dinv, N);
    k_scan1<<<nbN, SCAN_BS, 0, stream>>>(degi, incl, partial, N);
    k_scan2<<<1, SCAN_BS, 0, stream>>>(partial, pexcl, nbN);
    k_scan3<<<nbN, 256, 0, stream>>>(incl, degi, pexcl, row_ptr, cursor, N);
    k_scatter<<<nbE, 256, 0, stream>>>(src, dst, dinv, cursor, src_s, coef_s, E);

    // ---- weight/bias conversion (zero-padded) ----
    k_wt<<<dim3(Fp / 32, H1p / 32), dim3(32, 8), 0, stream>>>(W1, W1t, F, H1, Fp, H1p);
    k_wt<<<dim3(H1p / 32, H2p / 32), dim3(32, 8), 0, stream>>>(W2, W2t, H1, H2, H1p, H2p);
    k_wt<<<dim3(H2p / 32, H3p / 32), dim3(32, 8), 0, stream>>>(W3, W3t, H2, H3, H2p, H3p);
    k_biaspad<<<(H1p + 255) / 256, 256, 0, stream>>>(b1, b1p, H1, H1p);
    k_biaspad<<<(H2p + 255) / 256, 256, 0, stream>>>(b2, b2p, H2, H2p);
    k_biaspad<<<(H3p + 255) / 256, 256, 0, stream>>>(b3, b3p, H3, H3p);

    // ---- layer 1: agg(x) fp32->bf16 [N,128]; MFMA GEMM + b1 + relu -> bufB bf16 [Mp,1024]
    k_agg_f32<<<dim3((Fp / 4 + 63) / 64, N), 64, 0, stream>>>(
        x, bufA, row_ptr, src_s, coef_s, dinv, nullptr, Fp, 0, 1);
    k_gemm_bf16<<<dim3(H1p / 128, Mp / 128), 256, 0, stream>>>(
        bufA, W1t, b1p, bufB, N, Fp, H1p, 1, 1);

    // ---- layer 2: GEMM -> bufA bf16 [Mp,768]; agg + b2 + relu -> bufB bf16
    k_gemm_bf16<<<dim3(H2p / 128, Mp / 128), 256, 0, stream>>>(
        bufB, W2t, nullptr, bufA, N, H1p, H2p, 0, 1);
    k_agg_b16<<<dim3((H2p / 8 + 63) / 64, N), 64, 0, stream>>>(
        bufA, bufB, row_ptr, src_s, coef_s, dinv, b2p, H2p, 1);

    // ---- layer 3: GEMM -> bufA fp32 [Mp,256]; agg + b3 + relu -> bufB fp32
    k_gemm_bf16<<<dim3(H3p / 128, Mp / 128), 256, 0, stream>>>(
        bufB, W3t, nullptr, bufA, N, H2p, H3p, 0, 0);
    k_agg_f32<<<dim3((H3p / 4 + 63) / 64, N), 64, 0, stream>>>(
        (const float*)bufA, bufB, row_ptr, src_s, coef_s, dinv, b3p, H3p, 1, 0);

    // ---- pool + classifier ----
    k_pool<<<64, 256, 0, stream>>>((const float*)bufB, bat, pooled, N, H3, H3p);
    k_classifier<<<64, 64, 0, stream>>>(pooled, Wl, bl, (float*)d_out, H3, NC);
}

// Round 3
// 345.614 us; speedup vs baseline: 1.8309x; 1.0059x over previous
//
#include <hip/hip_runtime.h>
#include <hip/hip_bf16.h>
#include <stdint.h>

// ---------------------------------------------------------------------------
// simple_GCN: 3-layer GCNConv (N=10000, E=160000, 128->1000->700->200) +
// global mean pool (64 graphs) + linear(10).
//
// R3: layer-3 aggregation FUSED with mean-pool (atomicAdd into per-graph
// sums with graph-change flushing over sorted batch). The 49us latency-bound
// k_pool (64 blocks, 2% occupancy) is eliminated; GEMM3 outputs bf16 to
// halve the layer-3 gather bytes. GEMMs: bf16 MFMA m97 structure (128x128
// tile, BK=32, 16x16x32_bf16, global_load_lds width=16).
// ---------------------------------------------------------------------------

#define SCAN_BS 256

__device__ __forceinline__ uint16_t f2b(float f) {           // fp32->bf16 RNE
    union { float f; uint32_t u; } v; v.f = f;
    return (uint16_t)((v.u + 0x7fffu + ((v.u >> 16) & 1u)) >> 16);
}
__device__ __forceinline__ float blo(uint32_t u) { union { uint32_t u; float f; } v; v.u = u << 16; return v.f; }
__device__ __forceinline__ float bhi(uint32_t u) { union { uint32_t u; float f; } v; v.u = u & 0xffff0000u; return v.f; }

// ---------------- CSR build ----------------
__global__ void k_zero_int(int* __restrict__ p, int n) {
    int i = blockIdx.x * blockDim.x + threadIdx.x;
    if (i < n) p[i] = 0;
}
__global__ void k_count_deg(const int* __restrict__ dst, int* __restrict__ degi, int E) {
    int e = blockIdx.x * blockDim.x + threadIdx.x;
    if (e < E) atomicAdd(&degi[dst[e]], 1);
}
__global__ void k_dinv(const int* __restrict__ degi, float* __restrict__ dinv, int N) {
    int i = blockIdx.x * blockDim.x + threadIdx.x;
    if (i < N) dinv[i] = rsqrtf((float)degi[i] + 1.0f);
}
__global__ void k_scan1(const int* __restrict__ degi, int* __restrict__ incl,
                        int* __restrict__ partial, int N) {
    __shared__ int s[SCAN_BS];
    int t = threadIdx.x, i = blockIdx.x * SCAN_BS + t;
    int v = (i < N) ? degi[i] : 0;
    s[t] = v; __syncthreads();
    for (int o = 1; o < SCAN_BS; o <<= 1) {
        int add = (t >= o) ? s[t - o] : 0; __syncthreads();
        if (t >= o) s[t] += add; __syncthreads();
    }
    if (i < N) incl[i] = s[t];
    if (t == SCAN_BS - 1) partial[blockIdx.x] = s[t];
}
__global__ void k_scan2(const int* __restrict__ partial, int* __restrict__ part_excl, int nb) {
    __shared__ int s[SCAN_BS];
    int t = threadIdx.x;
    int v = (t < nb) ? partial[t] : 0;
    s[t] = v; __syncthreads();
    for (int o = 1; o < SCAN_BS; o <<= 1) {
        int add = (t >= o) ? s[t - o] : 0; __syncthreads();
        if (t >= o) s[t] += add; __syncthreads();
    }
    if (t < nb) part_excl[t] = s[t] - v;
}
__global__ void k_scan3(const int* __restrict__ incl, const int* __restrict__ degi,
                        const int* __restrict__ part_excl, int* __restrict__ row_ptr,
                        int* __restrict__ cursor, int N) {
    int i = blockIdx.x * blockDim.x + threadIdx.x;
    if (i < N) {
        int rp = incl[i] - degi[i] + part_excl[i >> 8];
        row_ptr[i] = rp; cursor[i] = rp;
        if (i == N - 1) row_ptr[N] = rp + degi[i];
    }
}
__global__ void k_scatter(const int* __restrict__ src, const int* __restrict__ dst,
                          const float* __restrict__ dinv, int* __restrict__ cursor,
                          int* __restrict__ src_s, float* __restrict__ coef_s, int E) {
    int e = blockIdx.x * blockDim.x + threadIdx.x;
    if (e < E) {
        int s = src[e], d = dst[e];
        int pos = atomicAdd(&cursor[d], 1);
        src_s[pos]  = s;
        coef_s[pos] = dinv[s] * dinv[d];
    }
}

// ---------------- weight transpose-convert (fp32 [K x N] -> bf16 [Np x Kp], zero-padded)
__global__ void k_wt(const float* __restrict__ W, uint16_t* __restrict__ Wt,
                     int K, int Nn, int Kp, int Np) {
    __shared__ float tile[32][33];
    int k0 = blockIdx.x * 32, n0 = blockIdx.y * 32;
    int tx = threadIdx.x, ty = threadIdx.y;  // 32 x 8
    for (int i = ty; i < 32; i += 8) {
        int k = k0 + i, n = n0 + tx;
        tile[i][tx] = (k < K && n < Nn) ? W[(size_t)k * Nn + n] : 0.f;
    }
    __syncthreads();
    for (int i = ty; i < 32; i += 8) {
        int n = n0 + i, k = k0 + tx;
        Wt[(size_t)n * Kp + k] = f2b(tile[tx][i]);
    }
}
__global__ void k_biaspad(const float* __restrict__ b, float* __restrict__ bp, int H, int Hp) {
    int i = blockIdx.x * blockDim.x + threadIdx.x;
    if (i < Hp) bp[i] = (i < H) ? b[i] : 0.f;
}

// ---------------- aggregation ----------------
// fp32 in, chunk=4; out fp32 or bf16
__global__ void k_agg_f32(const float* __restrict__ in, void* __restrict__ out,
                          const int* __restrict__ row_ptr, const int* __restrict__ src_s,
                          const float* __restrict__ coef_s, const float* __restrict__ dinv,
                          const float* __restrict__ bias, int Hp, int relu, int out_bf16) {
    int node = blockIdx.y;
    int j = blockIdx.x * blockDim.x + threadIdx.x;
    int Hc = Hp >> 2;
    if (j >= Hc) return;
    int rs = row_ptr[node], re = row_ptr[node + 1];
    float self = dinv[node]; self *= self;
    const float4* in4 = (const float4*)in;
    float4 xv = in4[(size_t)node * Hc + j];
    float a0 = self * xv.x, a1 = self * xv.y, a2 = self * xv.z, a3 = self * xv.w;
    for (int e = rs; e < re; ++e) {
        float c = coef_s[e]; int s = src_s[e];
        float4 hv = in4[(size_t)s * Hc + j];
        a0 += c * hv.x; a1 += c * hv.y; a2 += c * hv.z; a3 += c * hv.w;
    }
    if (bias) { float4 bv = ((const float4*)bias)[j]; a0 += bv.x; a1 += bv.y; a2 += bv.z; a3 += bv.w; }
    if (relu) { a0 = fmaxf(a0, 0.f); a1 = fmaxf(a1, 0.f); a2 = fmaxf(a2, 0.f); a3 = fmaxf(a3, 0.f); }
    if (out_bf16) {
        uint2 o;
        o.x = (uint32_t)f2b(a0) | ((uint32_t)f2b(a1) << 16);
        o.y = (uint32_t)f2b(a2) | ((uint32_t)f2b(a3) << 16);
        ((uint2*)out)[(size_t)node * Hc + j] = o;
    } else {
        float4 o; o.x = a0; o.y = a1; o.z = a2; o.w = a3;
        ((float4*)out)[(size_t)node * Hc + j] = o;
    }
}
// bf16 in/out, chunk=8 (uint4 = 16B)
__global__ void k_agg_b16(const uint16_t* __restrict__ in, uint16_t* __restrict__ out,
                          const int* __restrict__ row_ptr, const int* __restrict__ src_s,
                          const float* __restrict__ coef_s, const float* __restrict__ dinv,
                          const float* __restrict__ bias, int Hp, int relu) {
    int node = blockIdx.y;
    int j = blockIdx.x * blockDim.x + threadIdx.x;
    int Hc = Hp >> 3;
    if (j >= Hc) return;
    int rs = row_ptr[node], re = row_ptr[node + 1];
    float self = dinv[node]; self *= self;
    const uint4* in4 = (const uint4*)in;
    uint4 v = in4[(size_t)node * Hc + j];
    float a[8];
    a[0] = self * blo(v.x); a[1] = self * bhi(v.x);
    a[2] = self * blo(v.y); a[3] = self * bhi(v.y);
    a[4] = self * blo(v.z); a[5] = self * bhi(v.z);
    a[6] = self * blo(v.w); a[7] = self * bhi(v.w);
    for (int e = rs; e < re; ++e) {
        float c = coef_s[e]; int s = src_s[e];
        uint4 h = in4[(size_t)s * Hc + j];
        a[0] += c * blo(h.x); a[1] += c * bhi(h.x);
        a[2] += c * blo(h.y); a[3] += c * bhi(h.y);
        a[4] += c * blo(h.z); a[5] += c * bhi(h.z);
        a[6] += c * blo(h.w); a[7] += c * bhi(h.w);
    }
    if (bias) {
        const float4* b4 = (const float4*)bias;
        float4 b0 = b4[2 * j], b1 = b4[2 * j + 1];
        a[0] += b0.x; a[1] += b0.y; a[2] += b0.z; a[3] += b0.w;
        a[4] += b1.x; a[5] += b1.y; a[6] += b1.z; a[7] += b1.w;
    }
    if (relu) {
#pragma unroll
        for (int t = 0; t < 8; ++t) a[t] = fmaxf(a[t], 0.f);
    }
    uint4 o;
    o.x = (uint32_t)f2b(a[0]) | ((uint32_t)f2b(a[1]) << 16);
    o.y = (uint32_t)f2b(a[2]) | ((uint32_t)f2b(a[3]) << 16);
    o.z = (uint32_t)f2b(a[4]) | ((uint32_t)f2b(a[5]) << 16);
    o.w = (uint32_t)f2b(a[6]) | ((uint32_t)f2b(a[7]) << 16);
    ((uint4*)out)[(size_t)node * Hc + j] = o;
}

// ---------------- fused layer-3 aggregation + mean-pool accumulation ----------
// in: bf16 [Mp x Hp] (GEMM3 output). For each node: s = relu(agg + bias),
// accumulated per-thread across its 8 consecutive nodes; flushed to
// pooled_sum[g][...] via atomicAdd on graph change (batch sorted).
__global__ __launch_bounds__(256) void k_agg_pool(
    const uint16_t* __restrict__ in, float* __restrict__ pooled_sum,
    const int* __restrict__ row_ptr, const int* __restrict__ src_s,
    const float* __restrict__ coef_s, const float* __restrict__ dinv,
    const float* __restrict__ bias, const int* __restrict__ batch,
    int N, int H, int Hp) {
    int j    = threadIdx.x & 63;        // 4-feature chunk id
    int slot = threadIdx.x >> 6;        // 0..3, wave-uniform
    int Hc   = H >> 2;                  // 50 real chunks
    int HcP  = Hp >> 2;                 // padded stride in uint2 units (64)
    bool act = j < Hc;
    const uint2* in2 = (const uint2*)in;
    float b0 = 0.f, b1 = 0.f, b2 = 0.f, b3 = 0.f;
    if (act) { float4 bv = ((const float4*)bias)[j]; b0 = bv.x; b1 = bv.y; b2 = bv.z; b3 = bv.w; }
    float a0 = 0.f, a1 = 0.f, a2 = 0.f, a3 = 0.f;
    int gcur = -1;
    int base = blockIdx.x * 32 + slot * 8;   // this thread's 8 consecutive nodes
    for (int t = 0; t < 8; ++t) {
        int node = base + t;
        if (node >= N) break;
        int g = batch[node];
        if (g != gcur) {
            if (gcur >= 0 && act) {
                float* ps = &pooled_sum[(size_t)gcur * H + j * 4];
                atomicAdd(&ps[0], a0); atomicAdd(&ps[1], a1);
                atomicAdd(&ps[2], a2); atomicAdd(&ps[3], a3);
            }
            gcur = g; a0 = a1 = a2 = a3 = 0.f;
        }
        int rs = row_ptr[node], re = row_ptr[node + 1];
        float self = dinv[node]; self *= self;
        if (act) {
            uint2 v = in2[(size_t)node * HcP + j];
            float s0 = self * blo(v.x), s1 = self * bhi(v.x);
            float s2 = self * blo(v.y), s3 = self * bhi(v.y);
            for (int e = rs; e < re; ++e) {
                float c = coef_s[e]; int sn = src_s[e];
                uint2 h = in2[(size_t)sn * HcP + j];
                s0 += c * blo(h.x); s1 += c * bhi(h.x);
                s2 += c * blo(h.y); s3 += c * bhi(h.y);
            }
            a0 += fmaxf(s0 + b0, 0.f); a1 += fmaxf(s1 + b1, 0.f);
            a2 += fmaxf(s2 + b2, 0.f); a3 += fmaxf(s3 + b3, 0.f);
        }
    }
    if (gcur >= 0 && act) {
        float* ps = &pooled_sum[(size_t)gcur * H + j * 4];
        atomicAdd(&ps[0], a0); atomicAdd(&ps[1], a1);
        atomicAdd(&ps[2], a2); atomicAdd(&ps[3], a3);
    }
}

// ---------------- bf16 MFMA GEMM: C[M,Np] = act(A[Mp,Kp] @ Bt[Np,Kp]^T + bias)
typedef __attribute__((ext_vector_type(8))) short short8;
typedef __attribute__((ext_vector_type(4))) float floatx4;

#define LDSP(p) ((__attribute__((address_space(3))) void*)(uintptr_t)(p))
#define GLBP(p) ((const __attribute__((address_space(1))) void*)(uintptr_t)(p))

__global__ __launch_bounds__(256) void k_gemm_bf16(
    const uint16_t* __restrict__ A,   // [Mp x Kp] row-major, Kp%32==0
    const uint16_t* __restrict__ Bt,  // [Np x Kp] row-major (= W transposed)
    const float* __restrict__ bias,   // [Np] padded, or null
    void* __restrict__ Cout,          // bf16 or fp32 [.. x Np]
    int M, int Kp, int Np, int relu, int out_bf16) {
    __shared__ uint16_t As[128 * 32];
    __shared__ uint16_t Bs[128 * 32];
    int tid = threadIdx.x;
    int wave = tid >> 6, lane = tid & 63;
    int quad = lane >> 4, m16 = lane & 15;
    int wr = wave >> 1, wc = wave & 1;
    int row0 = blockIdx.y * 128, col0 = blockIdx.x * 128;

    int rA = tid >> 2, cA = tid & 3;            // staging: row, 16B chunk
    const uint16_t* gA = A  + (size_t)(row0 + rA) * Kp + cA * 8;
    const uint16_t* gB = Bt + (size_t)(col0 + rA) * Kp + cA * 8;
    uint16_t* lA = As + tid * 8;                // dst = wave base + lane*16B
    uint16_t* lB = Bs + tid * 8;
    size_t rowStep = (size_t)64 * Kp;

    floatx4 acc[4][4];
#pragma unroll
    for (int i = 0; i < 4; ++i)
#pragma unroll
        for (int j = 0; j < 4; ++j) acc[i][j] = (floatx4){0.f, 0.f, 0.f, 0.f};

    const short* Ash = (const short*)As;
    const short* Bsh = (const short*)Bs;
    int aBase = (wr * 64 + m16) * 32 + quad * 8;
    int bBase = (wc * 64 + m16) * 32 + quad * 8;

    for (int k0 = 0; k0 < Kp; k0 += 32) {
        __builtin_amdgcn_global_load_lds(GLBP(gA),           LDSP(lA),        16, 0, 0);
        __builtin_amdgcn_global_load_lds(GLBP(gA + rowStep), LDSP(lA + 2048), 16, 0, 0);
        __builtin_amdgcn_global_load_lds(GLBP(gB),           LDSP(lB),        16, 0, 0);
        __builtin_amdgcn_global_load_lds(GLBP(gB + rowStep), LDSP(lB + 2048), 16, 0, 0);
        gA += 32; gB += 32;
        __syncthreads();
        short8 af[4], bf[4];
#pragma unroll
        for (int i = 0; i < 4; ++i) af[i] = *(const short8*)&Ash[aBase + i * 512];
#pragma unroll
        for (int j = 0; j < 4; ++j) bf[j] = *(const short8*)&Bsh[bBase + j * 512];
#pragma unroll
        for (int i = 0; i < 4; ++i)
#pragma unroll
            for (int j = 0; j < 4; ++j)
                acc[i][j] = __builtin_amdgcn_mfma_f32_16x16x32_bf16(af[i], bf[j], acc[i][j], 0, 0, 0);
        __syncthreads();
    }

    float bv[4];
#pragma unroll
    for (int j = 0; j < 4; ++j) {
        int n = col0 + wc * 64 + j * 16 + m16;
        bv[j] = bias ? bias[n] : 0.f;
    }
#pragma unroll
    for (int i = 0; i < 4; ++i) {
        int mBase = row0 + wr * 64 + i * 16 + quad * 4;
#pragma unroll
        for (int r = 0; r < 4; ++r) {
            int m = mBase + r;
            if (m < M) {
#pragma unroll
                for (int j = 0; j < 4; ++j) {
                    int n = col0 + wc * 64 + j * 16 + m16;
                    float v = acc[i][j][r] + bv[j];
                    if (relu) v = fmaxf(v, 0.f);
                    if (out_bf16) ((uint16_t*)Cout)[(size_t)m * Np + n] = f2b(v);
                    else          ((float*)Cout)[(size_t)m * Np + n]    = v;
                }
            }
        }
    }
}

// ---------------- classifier (divides pooled sums by per-graph count) -------
__global__ void k_classifier(const float* __restrict__ pooled_sum,
                             const int* __restrict__ batch,
                             const float* __restrict__ Wl, const float* __restrict__ bl,
                             float* __restrict__ out, int N, int H, int NC) {
    int g = blockIdx.x, c = threadIdx.x;
    int lo = 0, hi = N;
    while (lo < hi) { int mid = (lo + hi) >> 1; if (batch[mid] < g) lo = mid + 1; else hi = mid; }
    int start = lo;
    lo = start; hi = N;
    while (lo < hi) { int mid = (lo + hi) >> 1; if (batch[mid] < g + 1) lo = mid + 1; else hi = mid; }
    int end = lo;
    float scale = 1.0f / fmaxf((float)(end - start), 1.0f);
    if (c < NC) {
        float acc = 0.f;
        for (int k = 0; k < H; ++k) acc += pooled_sum[(size_t)g * H + k] * Wl[(size_t)k * NC + c];
        out[(size_t)g * NC + c] = acc * scale + bl[c];
    }
}

static inline size_t align256(size_t x) { return (x + 255) & ~(size_t)255; }
static inline int pad128(int x) { return (x + 127) & ~127; }

extern "C" void kernel_launch(void* const* d_in, const int* in_sizes, int n_in,
                              void* d_out, int out_size, void* d_ws, size_t ws_size,
                              hipStream_t stream) {
    const float* x   = (const float*)d_in[0];
    const int*   ei  = (const int*)d_in[1];
    const int*   bat = (const int*)d_in[2];
    const float* W1  = (const float*)d_in[3];
    const float* b1  = (const float*)d_in[4];
    const float* W2  = (const float*)d_in[5];
    const float* b2  = (const float*)d_in[6];
    const float* W3  = (const float*)d_in[7];
    const float* b3  = (const float*)d_in[8];
    const float* Wl  = (const float*)d_in[9];
    const float* bl  = (const float*)d_in[10];

    const int N  = in_sizes[2];
    const int E  = in_sizes[1] / 2;
    const int F  = in_sizes[0] / N;    // 128
    const int H1 = in_sizes[4];        // 1000
    const int H2 = in_sizes[6];        // 700
    const int H3 = in_sizes[8];        // 200
    const int NC = in_sizes[10];       // 10
    const int G  = out_size / NC;      // 64
    const int* src = ei;
    const int* dst = ei + E;

    const int Mp  = pad128(N);         // 10112
    const int Fp  = F;                 // 128
    const int H1p = pad128(H1);        // 1024
    const int H2p = pad128(H2);        // 768
    const int H3p = pad128(H3);        // 256

    // workspace carve
    char* p = (char*)d_ws;
    size_t off = 0;
    auto carve = [&](size_t bytes) { void* q = p + off; off += align256(bytes); return q; };
    uint16_t* bufA   = (uint16_t*)carve((size_t)Mp * 2048);
    uint16_t* bufB   = (uint16_t*)carve((size_t)Mp * 2048);
    uint16_t* W1t    = (uint16_t*)carve((size_t)H1p * Fp * 2);
    uint16_t* W2t    = (uint16_t*)carve((size_t)H2p * H1p * 2);
    uint16_t* W3t    = (uint16_t*)carve((size_t)H3p * H2p * 2);
    float* b1p       = (float*)carve((size_t)H1p * 4);
    float* b2p       = (float*)carve((size_t)H2p * 4);
    float* dinv      = (float*)carve((size_t)N * 4);
    int*   degi      = (int*)carve((size_t)N * 4);
    int*   incl      = (int*)carve((size_t)N * 4);
    int*   partial   = (int*)carve(256 * 4);
    int*   pexcl     = (int*)carve(256 * 4);
    int*   row_ptr   = (int*)carve((size_t)(N + 1) * 4);
    int*   cursor    = (int*)carve((size_t)N * 4);
    int*   src_s     = (int*)carve((size_t)E * 4);
    float* coef_s    = (float*)carve((size_t)E * 4);
    float* pooled    = (float*)carve((size_t)G * H3 * 4);
    (void)ws_size;

    const int nbN = (N + 255) / 256;
    const int nbE = (E + 255) / 256;

    // ---- CSR build + pooled zero ----
    k_zero_int<<<nbN, 256, 0, stream>>>(degi, N);
    k_zero_int<<<(G * H3 + 255) / 256, 256, 0, stream>>>((int*)pooled, G * H3);
    k_count_deg<<<nbE, 256, 0, stream>>>(dst, degi, E);
    k_dinv<<<nbN, 256, 0, stream>>>(degi, dinv, N);
    k_scan1<<<nbN, SCAN_BS, 0, stream>>>(degi, incl, partial, N);
    k_scan2<<<1, SCAN_BS, 0, stream>>>(partial, pexcl, nbN);
    k_scan3<<<nbN, 256, 0, stream>>>(incl, degi, pexcl, row_ptr, cursor, N);
    k_scatter<<<nbE, 256, 0, stream>>>(src, dst, dinv, cursor, src_s, coef_s, E);

    // ---- weight/bias conversion (zero-padded) ----
    k_wt<<<dim3(Fp / 32, H1p / 32), dim3(32, 8), 0, stream>>>(W1, W1t, F, H1, Fp, H1p);
    k_wt<<<dim3(H1p / 32, H2p / 32), dim3(32, 8), 0, stream>>>(W2, W2t, H1, H2, H1p, H2p);
    k_wt<<<dim3(H2p / 32, H3p / 32), dim3(32, 8), 0, stream>>>(W3, W3t, H2, H3, H2p, H3p);
    k_biaspad<<<(H1p + 255) / 256, 256, 0, stream>>>(b1, b1p, H1, H1p);
    k_biaspad<<<(H2p + 255) / 256, 256, 0, stream>>>(b2, b2p, H2, H2p);

    // ---- layer 1: agg(x) fp32->bf16 [N,128]; GEMM + b1 + relu -> bufB bf16 [Mp,1024]
    k_agg_f32<<<dim3((Fp / 4 + 63) / 64, N), 64, 0, stream>>>(
        x, bufA, row_ptr, src_s, coef_s, dinv, nullptr, Fp, 0, 1);
    k_gemm_bf16<<<dim3(H1p / 128, Mp / 128), 256, 0, stream>>>(
        bufA, W1t, b1p, bufB, N, Fp, H1p, 1, 1);

    // ---- layer 2: GEMM -> bufA bf16 [Mp,768]; agg + b2 + relu -> bufB bf16
    k_gemm_bf16<<<dim3(H2p / 128, Mp / 128), 256, 0, stream>>>(
        bufB, W2t, nullptr, bufA, N, H1p, H2p, 0, 1);
    k_agg_b16<<<dim3((H2p / 8 + 63) / 64, N), 64, 0, stream>>>(
        bufA, bufB, row_ptr, src_s, coef_s, dinv, b2p, H2p, 1);

    // ---- layer 3: GEMM -> bufA bf16 [Mp,256]; fused agg + b3 + relu + pool
    k_gemm_bf16<<<dim3(H3p / 128, Mp / 128), 256, 0, stream>>>(
        bufB, W3t, nullptr, bufA, N, H2p, H3p, 0, 1);
    k_agg_pool<<<(N + 31) / 32, 256, 0, stream>>>(
        bufA, pooled, row_ptr, src_s, coef_s, dinv, b3, bat, N, H3, H3p);

    // ---- classifier ----
    k_classifier<<<G, 64, 0, stream>>>(pooled, bat, Wl, bl, (float*)d_out, N, H3, NC);
}

// Round 4
// 303.946 us; speedup vs baseline: 2.0819x; 1.1371x over previous
//
#include <hip/hip_runtime.h>
#include <hip/hip_bf16.h>
#include <stdint.h>

// ---------------------------------------------------------------------------
// simple_GCN: 3-layer GCNConv (N=10000, E=160000, 128->1000->700->200) +
// global mean pool (64 graphs) + linear(10).
//
// R4: un-fuse agg3+pool (R3's fusion was latency-bound: 1.2 waves/SIMD,
// 72.6us). Layer-3 agg back to one-block-per-node (640k threads, bf16 in,
// fp32 out); pool is a flat-parallel strip kernel (thread = feature-chunk x
// 16-node strip, flush-on-graph-change atomicAdd). GEMMs: bf16 MFMA m97
// structure (128x128 tile, BK=32, 16x16x32_bf16, global_load_lds width=16).
// ---------------------------------------------------------------------------

#define SCAN_BS 256

__device__ __forceinline__ uint16_t f2b(float f) {           // fp32->bf16 RNE
    union { float f; uint32_t u; } v; v.f = f;
    return (uint16_t)((v.u + 0x7fffu + ((v.u >> 16) & 1u)) >> 16);
}
__device__ __forceinline__ float blo(uint32_t u) { union { uint32_t u; float f; } v; v.u = u << 16; return v.f; }
__device__ __forceinline__ float bhi(uint32_t u) { union { uint32_t u; float f; } v; v.u = u & 0xffff0000u; return v.f; }

// ---------------- CSR build ----------------
__global__ void k_zero_int(int* __restrict__ p, int n) {
    int i = blockIdx.x * blockDim.x + threadIdx.x;
    if (i < n) p[i] = 0;
}
__global__ void k_count_deg(const int* __restrict__ dst, int* __restrict__ degi, int E) {
    int e = blockIdx.x * blockDim.x + threadIdx.x;
    if (e < E) atomicAdd(&degi[dst[e]], 1);
}
__global__ void k_dinv(const int* __restrict__ degi, float* __restrict__ dinv, int N) {
    int i = blockIdx.x * blockDim.x + threadIdx.x;
    if (i < N) dinv[i] = rsqrtf((float)degi[i] + 1.0f);
}
__global__ void k_scan1(const int* __restrict__ degi, int* __restrict__ incl,
                        int* __restrict__ partial, int N) {
    __shared__ int s[SCAN_BS];
    int t = threadIdx.x, i = blockIdx.x * SCAN_BS + t;
    int v = (i < N) ? degi[i] : 0;
    s[t] = v; __syncthreads();
    for (int o = 1; o < SCAN_BS; o <<= 1) {
        int add = (t >= o) ? s[t - o] : 0; __syncthreads();
        if (t >= o) s[t] += add; __syncthreads();
    }
    if (i < N) incl[i] = s[t];
    if (t == SCAN_BS - 1) partial[blockIdx.x] = s[t];
}
__global__ void k_scan2(const int* __restrict__ partial, int* __restrict__ part_excl, int nb) {
    __shared__ int s[SCAN_BS];
    int t = threadIdx.x;
    int v = (t < nb) ? partial[t] : 0;
    s[t] = v; __syncthreads();
    for (int o = 1; o < SCAN_BS; o <<= 1) {
        int add = (t >= o) ? s[t - o] : 0; __syncthreads();
        if (t >= o) s[t] += add; __syncthreads();
    }
    if (t < nb) part_excl[t] = s[t] - v;
}
__global__ void k_scan3(const int* __restrict__ incl, const int* __restrict__ degi,
                        const int* __restrict__ part_excl, int* __restrict__ row_ptr,
                        int* __restrict__ cursor, int N) {
    int i = blockIdx.x * blockDim.x + threadIdx.x;
    if (i < N) {
        int rp = incl[i] - degi[i] + part_excl[i >> 8];
        row_ptr[i] = rp; cursor[i] = rp;
        if (i == N - 1) row_ptr[N] = rp + degi[i];
    }
}
__global__ void k_scatter(const int* __restrict__ src, const int* __restrict__ dst,
                          const float* __restrict__ dinv, int* __restrict__ cursor,
                          int* __restrict__ src_s, float* __restrict__ coef_s, int E) {
    int e = blockIdx.x * blockDim.x + threadIdx.x;
    if (e < E) {
        int s = src[e], d = dst[e];
        int pos = atomicAdd(&cursor[d], 1);
        src_s[pos]  = s;
        coef_s[pos] = dinv[s] * dinv[d];
    }
}

// ---------------- weight transpose-convert (fp32 [K x N] -> bf16 [Np x Kp], zero-padded)
__global__ void k_wt(const float* __restrict__ W, uint16_t* __restrict__ Wt,
                     int K, int Nn, int Kp, int Np) {
    __shared__ float tile[32][33];
    int k0 = blockIdx.x * 32, n0 = blockIdx.y * 32;
    int tx = threadIdx.x, ty = threadIdx.y;  // 32 x 8
    for (int i = ty; i < 32; i += 8) {
        int k = k0 + i, n = n0 + tx;
        tile[i][tx] = (k < K && n < Nn) ? W[(size_t)k * Nn + n] : 0.f;
    }
    __syncthreads();
    for (int i = ty; i < 32; i += 8) {
        int n = n0 + i, k = k0 + tx;
        Wt[(size_t)n * Kp + k] = f2b(tile[tx][i]);
    }
}
__global__ void k_biaspad(const float* __restrict__ b, float* __restrict__ bp, int H, int Hp) {
    int i = blockIdx.x * blockDim.x + threadIdx.x;
    if (i < Hp) bp[i] = (i < H) ? b[i] : 0.f;
}

// ---------------- aggregation ----------------
// fp32 in, chunk=4; out fp32 or bf16
__global__ void k_agg_f32(const float* __restrict__ in, void* __restrict__ out,
                          const int* __restrict__ row_ptr, const int* __restrict__ src_s,
                          const float* __restrict__ coef_s, const float* __restrict__ dinv,
                          const float* __restrict__ bias, int Hp, int relu, int out_bf16) {
    int node = blockIdx.y;
    int j = blockIdx.x * blockDim.x + threadIdx.x;
    int Hc = Hp >> 2;
    if (j >= Hc) return;
    int rs = row_ptr[node], re = row_ptr[node + 1];
    float self = dinv[node]; self *= self;
    const float4* in4 = (const float4*)in;
    float4 xv = in4[(size_t)node * Hc + j];
    float a0 = self * xv.x, a1 = self * xv.y, a2 = self * xv.z, a3 = self * xv.w;
    for (int e = rs; e < re; ++e) {
        float c = coef_s[e]; int s = src_s[e];
        float4 hv = in4[(size_t)s * Hc + j];
        a0 += c * hv.x; a1 += c * hv.y; a2 += c * hv.z; a3 += c * hv.w;
    }
    if (bias) { float4 bv = ((const float4*)bias)[j]; a0 += bv.x; a1 += bv.y; a2 += bv.z; a3 += bv.w; }
    if (relu) { a0 = fmaxf(a0, 0.f); a1 = fmaxf(a1, 0.f); a2 = fmaxf(a2, 0.f); a3 = fmaxf(a3, 0.f); }
    if (out_bf16) {
        uint2 o;
        o.x = (uint32_t)f2b(a0) | ((uint32_t)f2b(a1) << 16);
        o.y = (uint32_t)f2b(a2) | ((uint32_t)f2b(a3) << 16);
        ((uint2*)out)[(size_t)node * Hc + j] = o;
    } else {
        float4 o; o.x = a0; o.y = a1; o.z = a2; o.w = a3;
        ((float4*)out)[(size_t)node * Hc + j] = o;
    }
}
// bf16 in, chunk=8 (uint4 = 16B); out bf16 (uint4) or fp32 (2x float4)
__global__ void k_agg_b16(const uint16_t* __restrict__ in, void* __restrict__ out,
                          const int* __restrict__ row_ptr, const int* __restrict__ src_s,
                          const float* __restrict__ coef_s, const float* __restrict__ dinv,
                          const float* __restrict__ bias, int Hp, int relu, int out_f32) {
    int node = blockIdx.y;
    int j = blockIdx.x * blockDim.x + threadIdx.x;
    int Hc = Hp >> 3;
    if (j >= Hc) return;
    int rs = row_ptr[node], re = row_ptr[node + 1];
    float self = dinv[node]; self *= self;
    const uint4* in4 = (const uint4*)in;
    uint4 v = in4[(size_t)node * Hc + j];
    float a[8];
    a[0] = self * blo(v.x); a[1] = self * bhi(v.x);
    a[2] = self * blo(v.y); a[3] = self * bhi(v.y);
    a[4] = self * blo(v.z); a[5] = self * bhi(v.z);
    a[6] = self * blo(v.w); a[7] = self * bhi(v.w);
    for (int e = rs; e < re; ++e) {
        float c = coef_s[e]; int s = src_s[e];
        uint4 h = in4[(size_t)s * Hc + j];
        a[0] += c * blo(h.x); a[1] += c * bhi(h.x);
        a[2] += c * blo(h.y); a[3] += c * bhi(h.y);
        a[4] += c * blo(h.z); a[5] += c * bhi(h.z);
        a[6] += c * blo(h.w); a[7] += c * bhi(h.w);
    }
    if (bias) {
        const float4* b4 = (const float4*)bias;
        float4 b0 = b4[2 * j], b1 = b4[2 * j + 1];
        a[0] += b0.x; a[1] += b0.y; a[2] += b0.z; a[3] += b0.w;
        a[4] += b1.x; a[5] += b1.y; a[6] += b1.z; a[7] += b1.w;
    }
    if (relu) {
#pragma unroll
        for (int t = 0; t < 8; ++t) a[t] = fmaxf(a[t], 0.f);
    }
    if (out_f32) {
        float4* o4 = (float4*)out;
        float4 o0; o0.x = a[0]; o0.y = a[1]; o0.z = a[2]; o0.w = a[3];
        float4 o1; o1.x = a[4]; o1.y = a[5]; o1.z = a[6]; o1.w = a[7];
        o4[(size_t)node * (Hc * 2) + 2 * j]     = o0;
        o4[(size_t)node * (Hc * 2) + 2 * j + 1] = o1;
    } else {
        uint4 o;
        o.x = (uint32_t)f2b(a[0]) | ((uint32_t)f2b(a[1]) << 16);
        o.y = (uint32_t)f2b(a[2]) | ((uint32_t)f2b(a[3]) << 16);
        o.z = (uint32_t)f2b(a[4]) | ((uint32_t)f2b(a[5]) << 16);
        o.w = (uint32_t)f2b(a[6]) | ((uint32_t)f2b(a[7]) << 16);
        ((uint4*)out)[(size_t)node * Hc + j] = o;
    }
}

// ---------------- flat-parallel mean-pool accumulation ----------------------
// h: fp32 [Mp x Hp] (valid rows < N, feats < H). thread = (float4 chunk j,
// 16-node strip); fp32 accumulate, flush to pooled_sum[g] on graph change.
__global__ __launch_bounds__(256) void k_pool_fast(
    const float* __restrict__ h, const int* __restrict__ batch,
    float* __restrict__ pooled_sum, int N, int H, int Hp) {
    int j    = threadIdx.x & 63;          // float4 chunk id
    int slot = threadIdx.x >> 6;          // 0..3 (wave-uniform)
    int Hc   = H >> 2;                    // 50 real chunks
    if (j >= Hc) return;
    int HcP  = Hp >> 2;                   // 64 padded chunks
    const float4* h4 = (const float4*)h;
    int base = (blockIdx.x * 4 + slot) * 16;
    float a0 = 0.f, a1 = 0.f, a2 = 0.f, a3 = 0.f;
    int gcur = -1;
#pragma unroll 4
    for (int t = 0; t < 16; ++t) {
        int node = base + t;
        if (node < N) {
            int g = batch[node];
            if (g != gcur) {
                if (gcur >= 0) {
                    float* ps = &pooled_sum[(size_t)gcur * H + j * 4];
                    atomicAdd(&ps[0], a0); atomicAdd(&ps[1], a1);
                    atomicAdd(&ps[2], a2); atomicAdd(&ps[3], a3);
                }
                gcur = g; a0 = a1 = a2 = a3 = 0.f;
            }
            float4 v = h4[(size_t)node * HcP + j];
            a0 += v.x; a1 += v.y; a2 += v.z; a3 += v.w;
        }
    }
    if (gcur >= 0) {
        float* ps = &pooled_sum[(size_t)gcur * H + j * 4];
        atomicAdd(&ps[0], a0); atomicAdd(&ps[1], a1);
        atomicAdd(&ps[2], a2); atomicAdd(&ps[3], a3);
    }
}

// ---------------- bf16 MFMA GEMM: C[M,Np] = act(A[Mp,Kp] @ Bt[Np,Kp]^T + bias)
typedef __attribute__((ext_vector_type(8))) short short8;
typedef __attribute__((ext_vector_type(4))) float floatx4;

#define LDSP(p) ((__attribute__((address_space(3))) void*)(uintptr_t)(p))
#define GLBP(p) ((const __attribute__((address_space(1))) void*)(uintptr_t)(p))

__global__ __launch_bounds__(256) void k_gemm_bf16(
    const uint16_t* __restrict__ A,   // [Mp x Kp] row-major, Kp%32==0
    const uint16_t* __restrict__ Bt,  // [Np x Kp] row-major (= W transposed)
    const float* __restrict__ bias,   // [Np] padded, or null
    void* __restrict__ Cout,          // bf16 or fp32 [.. x Np]
    int M, int Kp, int Np, int relu, int out_bf16) {
    __shared__ uint16_t As[128 * 32];
    __shared__ uint16_t Bs[128 * 32];
    int tid = threadIdx.x;
    int wave = tid >> 6, lane = tid & 63;
    int quad = lane >> 4, m16 = lane & 15;
    int wr = wave >> 1, wc = wave & 1;
    int row0 = blockIdx.y * 128, col0 = blockIdx.x * 128;

    int rA = tid >> 2, cA = tid & 3;            // staging: row, 16B chunk
    const uint16_t* gA = A  + (size_t)(row0 + rA) * Kp + cA * 8;
    const uint16_t* gB = Bt + (size_t)(col0 + rA) * Kp + cA * 8;
    uint16_t* lA = As + tid * 8;                // dst = wave base + lane*16B
    uint16_t* lB = Bs + tid * 8;
    size_t rowStep = (size_t)64 * Kp;

    floatx4 acc[4][4];
#pragma unroll
    for (int i = 0; i < 4; ++i)
#pragma unroll
        for (int j = 0; j < 4; ++j) acc[i][j] = (floatx4){0.f, 0.f, 0.f, 0.f};

    const short* Ash = (const short*)As;
    const short* Bsh = (const short*)Bs;
    int aBase = (wr * 64 + m16) * 32 + quad * 8;
    int bBase = (wc * 64 + m16) * 32 + quad * 8;

    for (int k0 = 0; k0 < Kp; k0 += 32) {
        __builtin_amdgcn_global_load_lds(GLBP(gA),           LDSP(lA),        16, 0, 0);
        __builtin_amdgcn_global_load_lds(GLBP(gA + rowStep), LDSP(lA + 2048), 16, 0, 0);
        __builtin_amdgcn_global_load_lds(GLBP(gB),           LDSP(lB),        16, 0, 0);
        __builtin_amdgcn_global_load_lds(GLBP(gB + rowStep), LDSP(lB + 2048), 16, 0, 0);
        gA += 32; gB += 32;
        __syncthreads();
        short8 af[4], bf[4];
#pragma unroll
        for (int i = 0; i < 4; ++i) af[i] = *(const short8*)&Ash[aBase + i * 512];
#pragma unroll
        for (int j = 0; j < 4; ++j) bf[j] = *(const short8*)&Bsh[bBase + j * 512];
#pragma unroll
        for (int i = 0; i < 4; ++i)
#pragma unroll
            for (int j = 0; j < 4; ++j)
                acc[i][j] = __builtin_amdgcn_mfma_f32_16x16x32_bf16(af[i], bf[j], acc[i][j], 0, 0, 0);
        __syncthreads();
    }

    float bv[4];
#pragma unroll
    for (int j = 0; j < 4; ++j) {
        int n = col0 + wc * 64 + j * 16 + m16;
        bv[j] = bias ? bias[n] : 0.f;
    }
#pragma unroll
    for (int i = 0; i < 4; ++i) {
        int mBase = row0 + wr * 64 + i * 16 + quad * 4;
#pragma unroll
        for (int r = 0; r < 4; ++r) {
            int m = mBase + r;
            if (m < M) {
#pragma unroll
                for (int j = 0; j < 4; ++j) {
                    int n = col0 + wc * 64 + j * 16 + m16;
                    float v = acc[i][j][r] + bv[j];
                    if (relu) v = fmaxf(v, 0.f);
                    if (out_bf16) ((uint16_t*)Cout)[(size_t)m * Np + n] = f2b(v);
                    else          ((float*)Cout)[(size_t)m * Np + n]    = v;
                }
            }
        }
    }
}

// ---------------- classifier (divides pooled sums by per-graph count) -------
__global__ void k_classifier(const float* __restrict__ pooled_sum,
                             const int* __restrict__ batch,
                             const float* __restrict__ Wl, const float* __restrict__ bl,
                             float* __restrict__ out, int N, int H, int NC) {
    int g = blockIdx.x, c = threadIdx.x;
    int lo = 0, hi = N;
    while (lo < hi) { int mid = (lo + hi) >> 1; if (batch[mid] < g) lo = mid + 1; else hi = mid; }
    int start = lo;
    lo = start; hi = N;
    while (lo < hi) { int mid = (lo + hi) >> 1; if (batch[mid] < g + 1) lo = mid + 1; else hi = mid; }
    int end = lo;
    float scale = 1.0f / fmaxf((float)(end - start), 1.0f);
    if (c < NC) {
        float acc = 0.f;
        for (int k = 0; k < H; ++k) acc += pooled_sum[(size_t)g * H + k] * Wl[(size_t)k * NC + c];
        out[(size_t)g * NC + c] = acc * scale + bl[c];
    }
}

static inline size_t align256(size_t x) { return (x + 255) & ~(size_t)255; }
static inline int pad128(int x) { return (x + 127) & ~127; }

extern "C" void kernel_launch(void* const* d_in, const int* in_sizes, int n_in,
                              void* d_out, int out_size, void* d_ws, size_t ws_size,
                              hipStream_t stream) {
    const float* x   = (const float*)d_in[0];
    const int*   ei  = (const int*)d_in[1];
    const int*   bat = (const int*)d_in[2];
    const float* W1  = (const float*)d_in[3];
    const float* b1  = (const float*)d_in[4];
    const float* W2  = (const float*)d_in[5];
    const float* b2  = (const float*)d_in[6];
    const float* W3  = (const float*)d_in[7];
    const float* b3  = (const float*)d_in[8];
    const float* Wl  = (const float*)d_in[9];
    const float* bl  = (const float*)d_in[10];

    const int N  = in_sizes[2];
    const int E  = in_sizes[1] / 2;
    const int F  = in_sizes[0] / N;    // 128
    const int H1 = in_sizes[4];        // 1000
    const int H2 = in_sizes[6];        // 700
    const int H3 = in_sizes[8];        // 200
    const int NC = in_sizes[10];       // 10
    const int G  = out_size / NC;      // 64
    const int* src = ei;
    const int* dst = ei + E;

    const int Mp  = pad128(N);         // 10112
    const int Fp  = F;                 // 128
    const int H1p = pad128(H1);        // 1024
    const int H2p = pad128(H2);        // 768
    const int H3p = pad128(H3);        // 256

    // workspace carve
    char* p = (char*)d_ws;
    size_t off = 0;
    auto carve = [&](size_t bytes) { void* q = p + off; off += align256(bytes); return q; };
    uint16_t* bufA   = (uint16_t*)carve((size_t)Mp * 2048);   // holds up to Mp x 1024 bf16
    uint16_t* bufB   = (uint16_t*)carve((size_t)Mp * 2048);   // also holds Mp x 256 fp32 (2048 B/row)
    uint16_t* W1t    = (uint16_t*)carve((size_t)H1p * Fp * 2);
    uint16_t* W2t    = (uint16_t*)carve((size_t)H2p * H1p * 2);
    uint16_t* W3t    = (uint16_t*)carve((size_t)H3p * H2p * 2);
    float* b1p       = (float*)carve((size_t)H1p * 4);
    float* b2p       = (float*)carve((size_t)H2p * 4);
    float* b3p       = (float*)carve((size_t)H3p * 4);
    float* dinv      = (float*)carve((size_t)N * 4);
    int*   degi      = (int*)carve((size_t)N * 4);
    int*   incl      = (int*)carve((size_t)N * 4);
    int*   partial   = (int*)carve(256 * 4);
    int*   pexcl     = (int*)carve(256 * 4);
    int*   row_ptr   = (int*)carve((size_t)(N + 1) * 4);
    int*   cursor    = (int*)carve((size_t)N * 4);
    int*   src_s     = (int*)carve((size_t)E * 4);
    float* coef_s    = (float*)carve((size_t)E * 4);
    float* pooled    = (float*)carve((size_t)G * H3 * 4);
    (void)ws_size;

    const int nbN = (N + 255) / 256;
    const int nbE = (E + 255) / 256;

    // ---- CSR build + pooled zero ----
    k_zero_int<<<nbN, 256, 0, stream>>>(degi, N);
    k_zero_int<<<(G * H3 + 255) / 256, 256, 0, stream>>>((int*)pooled, G * H3);
    k_count_deg<<<nbE, 256, 0, stream>>>(dst, degi, E);
    k_dinv<<<nbN, 256, 0, stream>>>(degi, dinv, N);
    k_scan1<<<nbN, SCAN_BS, 0, stream>>>(degi, incl, partial, N);
    k_scan2<<<1, SCAN_BS, 0, stream>>>(partial, pexcl, nbN);
    k_scan3<<<nbN, 256, 0, stream>>>(incl, degi, pexcl, row_ptr, cursor, N);
    k_scatter<<<nbE, 256, 0, stream>>>(src, dst, dinv, cursor, src_s, coef_s, E);

    // ---- weight/bias conversion (zero-padded) ----
    k_wt<<<dim3(Fp / 32, H1p / 32), dim3(32, 8), 0, stream>>>(W1, W1t, F, H1, Fp, H1p);
    k_wt<<<dim3(H1p / 32, H2p / 32), dim3(32, 8), 0, stream>>>(W2, W2t, H1, H2, H1p, H2p);
    k_wt<<<dim3(H2p / 32, H3p / 32), dim3(32, 8), 0, stream>>>(W3, W3t, H2, H3, H2p, H3p);
    k_biaspad<<<(H1p + 255) / 256, 256, 0, stream>>>(b1, b1p, H1, H1p);
    k_biaspad<<<(H2p + 255) / 256, 256, 0, stream>>>(b2, b2p, H2, H2p);
    k_biaspad<<<(H3p + 255) / 256, 256, 0, stream>>>(b3, b3p, H3, H3p);

    // ---- layer 1: agg(x) fp32->bf16 [N,128]; GEMM + b1 + relu -> bufB bf16 [Mp,1024]
    k_agg_f32<<<dim3((Fp / 4 + 63) / 64, N), 64, 0, stream>>>(
        x, bufA, row_ptr, src_s, coef_s, dinv, nullptr, Fp, 0, 1);
    k_gemm_bf16<<<dim3(H1p / 128, Mp / 128), 256, 0, stream>>>(
        bufA, W1t, b1p, bufB, N, Fp, H1p, 1, 1);

    // ---- layer 2: GEMM -> bufA bf16 [Mp,768]; agg + b2 + relu -> bufB bf16
    k_gemm_bf16<<<dim3(H2p / 128, Mp / 128), 256, 0, stream>>>(
        bufB, W2t, nullptr, bufA, N, H1p, H2p, 0, 1);
    k_agg_b16<<<dim3((H2p / 8 + 63) / 64, N), 64, 0, stream>>>(
        bufA, bufB, row_ptr, src_s, coef_s, dinv, b2p, H2p, 1, 0);

    // ---- layer 3: GEMM -> bufA bf16 [Mp,256]; agg + b3 + relu -> bufB fp32 [Mp,256]
    k_gemm_bf16<<<dim3(H3p / 128, Mp / 128), 256, 0, stream>>>(
        bufB, W3t, nullptr, bufA, N, H2p, H3p, 0, 1);
    k_agg_b16<<<dim3((H3p / 8 + 63) / 64, N), 64, 0, stream>>>(
        bufA, bufB, row_ptr, src_s, coef_s, dinv, b3p, H3p, 1, 1);

    // ---- pool (flat-parallel, atomicAdd flush) + classifier ----
    k_pool_fast<<<(N + 63) / 64, 256, 0, stream>>>(
        (const float*)bufB, bat, pooled, N, H3, H3p);
    k_classifier<<<G, 64, 0, stream>>>(pooled, bat, Wl, bl, (float*)d_out, N, H3, NC);
}